// Round 5
// baseline (333.104 us; speedup 1.0000x reference)
//
#include <hip/hip_runtime.h>
#include <math.h>

#define BB   32      // batch
#define NN   1024    // nodes
#define DIN  2
#define DOUT 64
#define CIN  66      // DIN + DOUT
#define TD   32
#define ED   10
#define OG   128     // 2*DOUT (gate out)
#define OU   64      // upd out
#define KP   160     // padded K for the einsum GEMM (132 real)
#define XTR  80      // XTg rows per batch (68 data + 12 zero pad)

typedef __bf16 bf16x8 __attribute__((ext_vector_type(8)));
typedef float  f32x4  __attribute__((ext_vector_type(4)));
typedef short  s16x8  __attribute__((ext_vector_type(8)));

__device__ __forceinline__ unsigned short f2b(float f) {
    __bf16 h = (__bf16)f;
    return *(unsigned short*)&h;
}

// ---------------------------------------------------------------------------
template<int MODE>
__device__ __forceinline__ float loadX(const float* __restrict__ x,
                                       const float* __restrict__ state,
                                       const float* __restrict__ zr,
                                       int b, int m, int c)
{
    if (c < DIN) return x[((size_t)b*NN + m)*DIN + c];
    int j = c - DIN;
    float s = state[((size_t)b*NN + m)*DOUT + j];
    if (MODE == 1) s *= zr[((size_t)b*NN + m)*OG + j];
    return s;
}

// ---------------------------------------------------------------------------
// K1: tiny MLPs -> nv1, nv2 (bf16 out). One thread per (b,n).
// ---------------------------------------------------------------------------
__global__ __launch_bounds__(256) void k_nv(
    const float* __restrict__ x, const float* __restrict__ state,
    const float* __restrict__ ne0, const float* __restrict__ ne1,
    const float* __restrict__ w11, const float* __restrict__ b11,
    const float* __restrict__ w12, const float* __restrict__ b12,
    const float* __restrict__ w13, const float* __restrict__ b13,
    const float* __restrict__ w21, const float* __restrict__ b21,
    const float* __restrict__ w22, const float* __restrict__ b22,
    const float* __restrict__ w23, const float* __restrict__ b23,
    unsigned short* __restrict__ nv1b, unsigned short* __restrict__ nv2b)
{
    const int oW1 = 0, oB1 = 1056, oW2 = 1072, oB2 = 1104, oW3 = 1108, oB3 = 1172, F2 = 1204;
    __shared__ float sw[2408];
    int t = threadIdx.x;
    for (int i = t; i < 1056; i += 256) { sw[oW1+i] = w11[i]; sw[F2+oW1+i] = w21[i]; }
    if (t < 16) { sw[oB1+t] = b11[t]; sw[F2+oB1+t] = b21[t]; }
    if (t < 32) { sw[oW2+t] = w12[t]; sw[F2+oW2+t] = w22[t]; }
    if (t < 2)  { sw[oB2+t] = b12[t]; sw[F2+oB2+t] = b22[t]; }
    if (t < 64) { sw[oW3+t] = w13[t]; sw[F2+oW3+t] = w23[t]; }
    if (t >= 64 && t < 96) { sw[oB3+t-64] = b13[t-64]; sw[F2+oB3+t-64] = b23[t-64]; }
    __syncthreads();

    int p = blockIdx.x*256 + t;
    int b = p >> 10;

    float h1a[16], h1b[16];
    #pragma unroll
    for (int j = 0; j < 16; ++j) { h1a[j] = sw[oB1+j]; h1b[j] = sw[F2+oB1+j]; }
    for (int i = 0; i < CIN; ++i) {
        float v = (i < DIN) ? x[(size_t)p*DIN + i] : state[(size_t)p*DOUT + (i-DIN)];
        #pragma unroll
        for (int jq = 0; jq < 4; ++jq) {
            float4 wa = *(const float4*)&sw[oW1 + i*16 + jq*4];
            float4 wb = *(const float4*)&sw[F2 + oW1 + i*16 + jq*4];
            h1a[jq*4+0] += v*wa.x; h1a[jq*4+1] += v*wa.y;
            h1a[jq*4+2] += v*wa.z; h1a[jq*4+3] += v*wa.w;
            h1b[jq*4+0] += v*wb.x; h1b[jq*4+1] += v*wb.y;
            h1b[jq*4+2] += v*wb.z; h1b[jq*4+3] += v*wb.w;
        }
    }
    #pragma unroll
    for (int j = 0; j < 16; ++j) {
        h1a[j] = 1.f/(1.f + __expf(-h1a[j]));
        h1b[j] = 1.f/(1.f + __expf(-h1b[j]));
    }
    float h2a0 = sw[oB2+0], h2a1 = sw[oB2+1];
    float h2b0 = sw[F2+oB2+0], h2b1 = sw[F2+oB2+1];
    #pragma unroll
    for (int i = 0; i < 16; ++i) {
        h2a0 += h1a[i]*sw[oW2 + i*2 + 0];
        h2a1 += h1a[i]*sw[oW2 + i*2 + 1];
        h2b0 += h1b[i]*sw[F2+oW2 + i*2 + 0];
        h2b1 += h1b[i]*sw[F2+oW2 + i*2 + 1];
    }
    h2a0 = 1.f/(1.f + __expf(-h2a0)); h2a1 = 1.f/(1.f + __expf(-h2a1));
    h2b0 = 1.f/(1.f + __expf(-h2b0)); h2b1 = 1.f/(1.f + __expf(-h2b1));

    const float* pn0 = ne0 + b*TD;
    const float* pn1 = ne1 + b*TD;
    #pragma unroll
    for (int jq = 0; jq < 8; ++jq) {
        float4 ba  = *(const float4*)&sw[oB3 + jq*4];
        float4 wa0 = *(const float4*)&sw[oW3 + jq*4];
        float4 wa1 = *(const float4*)&sw[oW3 + 32 + jq*4];
        float4 bb2 = *(const float4*)&sw[F2+oB3 + jq*4];
        float4 wb0 = *(const float4*)&sw[F2+oW3 + jq*4];
        float4 wb1 = *(const float4*)&sw[F2+oW3 + 32 + jq*4];
        float4 n0 = *(const float4*)&pn0[jq*4];
        float4 n1 = *(const float4*)&pn1[jq*4];
        ushort4 u1, u2;
        u1.x = f2b(tanhf(n0.x*(ba.x + h2a0*wa0.x + h2a1*wa1.x)));
        u1.y = f2b(tanhf(n0.y*(ba.y + h2a0*wa0.y + h2a1*wa1.y)));
        u1.z = f2b(tanhf(n0.z*(ba.z + h2a0*wa0.z + h2a1*wa1.z)));
        u1.w = f2b(tanhf(n0.w*(ba.w + h2a0*wa0.w + h2a1*wa1.w)));
        u2.x = f2b(tanhf(n1.x*(bb2.x + h2b0*wb0.x + h2b1*wb1.x)));
        u2.y = f2b(tanhf(n1.y*(bb2.y + h2b0*wb0.y + h2b1*wb1.y)));
        u2.z = f2b(tanhf(n1.z*(bb2.z + h2b0*wb0.z + h2b1*wb1.z)));
        u2.w = f2b(tanhf(n1.w*(bb2.w + h2b0*wb0.w + h2b1*wb1.w)));
        *(ushort4*)&nv1b[(size_t)p*TD + jq*4] = u1;
        *(ushort4*)&nv2b[(size_t)p*TD + jq*4] = u2;
    }
}

// ---------------------------------------------------------------------------
// K_BC: combined pool matrices, K-transposed, bf16.
// ---------------------------------------------------------------------------
__global__ __launch_bounds__(256) void k_bc(
    const float* __restrict__ gate_w, const float* __restrict__ upd_w,
    unsigned short* __restrict__ BcTg, unsigned short* __restrict__ BcTu)
{
    int tid = blockIdx.x*256 + threadIdx.x;       // < 1920*160
    int c = tid / KP, k = tid - c*KP;
    const float* pool; int O, cc; unsigned short* dst;
    if (c < 1280) { pool = gate_w; O = OG; cc = c;        dst = BcTg; }
    else          { pool = upd_w;  O = OU; cc = c - 1280; dst = BcTu; }
    int d = cc / O, o = cc - d*O;
    float v = 0.f;
    if (k < 132) {
        int kp = (k < 66) ? 0 : 1;
        int i  = (k < 66) ? k : k - 66;
        v = pool[(size_t)((d*4 + kp)*CIN + i)*O + o]
          + pool[(size_t)((d*4 + kp + 2)*CIN + i)*O + o];
    }
    dst[(size_t)cc*KP + k] = f2b(v);
}

// ---------------------------------------------------------------------------
// K_XT: XTg[b][80][1024] bf16 (rows 0-1 x, 2-65 state/z*state, 66 ones,
// 67..79 zeros). m-contiguous so PV B-frags can be loaded direct from global.
// ---------------------------------------------------------------------------
template<int MODE>
__global__ __launch_bounds__(256) void k_xt(
    const float* __restrict__ x, const float* __restrict__ state,
    const float* __restrict__ zr, unsigned short* __restrict__ XTg)
{
    __shared__ unsigned short st[68*72];
    int t = threadIdx.x;
    int b = blockIdx.y, m0 = blockIdx.x*64;
    for (int i = t; i < 1024; i += 256) {
        int m = i >> 4, cq = i & 15;
        size_t base = (size_t)b*NN + m0 + m;
        float4 v = *(const float4*)&state[base*DOUT + cq*4];
        if (MODE == 1) {
            float4 z = *(const float4*)&zr[base*OG + cq*4];
            v.x *= z.x; v.y *= z.y; v.z *= z.z; v.w *= z.w;
        }
        st[(2 + cq*4 + 0)*72 + m] = f2b(v.x);
        st[(2 + cq*4 + 1)*72 + m] = f2b(v.y);
        st[(2 + cq*4 + 2)*72 + m] = f2b(v.z);
        st[(2 + cq*4 + 3)*72 + m] = f2b(v.w);
    }
    if (t < 128) {
        int m = t >> 1, c = t & 1;
        st[c*72 + m] = f2b(x[((size_t)b*NN + m0 + m)*DIN + c]);
    }
    __syncthreads();
    const unsigned int ONE2 = 0x3F803F80u;
    for (int i = t; i < XTR*8; i += 256) {
        int c = i >> 3, ch = i & 7;
        uint4 v;
        if (c < 66)      v = *(const uint4*)&st[c*72 + ch*8];
        else if (c == 66) v = make_uint4(ONE2, ONE2, ONE2, ONE2);
        else              v = make_uint4(0, 0, 0, 0);
        *(uint4*)&XTg[((size_t)b*XTR + c)*1024 + m0 + ch*8] = v;
    }
}

// ---------------------------------------------------------------------------
// K3 v3: fused A-apply, BARRIER-FREE. All MFMA B-frags loaded direct from
// global (L2-hot); P is wave-private LDS (lgkm-ordered within wave); rowsum
// via ones-column + __shfl. Epilogue emits GEMM A rows bf16:
//   A[row][0..65]=X, A[row][66..131]=(relu(adj)@X+X)/(1+rs), [132..159]=0.
// ---------------------------------------------------------------------------
template<int MODE>
__global__ __launch_bounds__(256) void k_aapply(
    const unsigned short* __restrict__ nv1b, const unsigned short* __restrict__ nv2b,
    const unsigned short* __restrict__ XTg,
    const float* __restrict__ x, const float* __restrict__ state,
    const float* __restrict__ zr, unsigned short* __restrict__ A)
{
    __shared__ unsigned short s_p[4][16*72];   // wave-private P, 9.2 KB

    int t = threadIdx.x;
    int b = blockIdx.y, rbase = blockIdx.x*64;
    int w = t >> 6, lane = t & 63, lq = lane >> 4, ln = lane & 15;
    int row16 = rbase + 16*w;                  // this wave's 16 rows

    // A-side fragments: rows, direct from global
    bf16x8 a1 = *(const bf16x8*)&nv1b[((size_t)b*NN + row16 + ln)*TD + lq*8];
    s16x8 a2s = *(const s16x8*)&nv2b[((size_t)b*NN + row16 + ln)*TD + lq*8];
    const s16x8 sgn = {(short)0x8000,(short)0x8000,(short)0x8000,(short)0x8000,
                       (short)0x8000,(short)0x8000,(short)0x8000,(short)0x8000};
    a2s ^= sgn;
    bf16x8 a2n = (bf16x8)a2s;                  // -nv2r (exact sign flip)

    f32x4 acc[5];
    #pragma unroll
    for (int i = 0; i < 5; ++i) acc[i] = (f32x4){0.f,0.f,0.f,0.f};
    const f32x4 zero4 = {0.f,0.f,0.f,0.f};

    const size_t nvB = (size_t)b*NN;
    const size_t xtB = (size_t)b*XTR;

    #pragma unroll 2
    for (int mb = 0; mb < NN; mb += 64) {
        // ---- S phase: S = nv1r.nv2c^T - nv2r.nv1c^T, relu -> wave-private P
        #pragma unroll
        for (int j0t = 0; j0t < 4; ++j0t) {
            int col = mb + j0t*16 + ln;
            bf16x8 b2 = *(const bf16x8*)&nv2b[(nvB + col)*TD + lq*8];
            bf16x8 b1 = *(const bf16x8*)&nv1b[(nvB + col)*TD + lq*8];
            f32x4 s = __builtin_amdgcn_mfma_f32_16x16x32_bf16(a1,  b2, zero4, 0, 0, 0);
            s       = __builtin_amdgcn_mfma_f32_16x16x32_bf16(a2n, b1, s,     0, 0, 0);
            #pragma unroll
            for (int r = 0; r < 4; ++r) {
                float p = fmaxf(s[r], 0.f);
                *(__bf16*)&s_p[w][(lq*4 + r)*72 + j0t*16 + ln] = (__bf16)p;
            }
        }

        // ---- PV phase: acc += P(16x64) @ XT(64x80)
        bf16x8 pa0 = *(const bf16x8*)&s_p[w][ln*72 +      lq*8];
        bf16x8 pa1 = *(const bf16x8*)&s_p[w][ln*72 + 32 + lq*8];
        #pragma unroll
        for (int n0t = 0; n0t < 5; ++n0t) {
            const unsigned short* xrow = &XTg[(xtB + n0t*16 + ln)*1024 + mb];
            bf16x8 xb0 = *(const bf16x8*)&xrow[     lq*8];
            bf16x8 xb1 = *(const bf16x8*)&xrow[32 + lq*8];
            acc[n0t] = __builtin_amdgcn_mfma_f32_16x16x32_bf16(pa0, xb0, acc[n0t], 0, 0, 0);
            acc[n0t] = __builtin_amdgcn_mfma_f32_16x16x32_bf16(pa1, xb1, acc[n0t], 0, 0, 0);
        }
    }

    // rowsum = output col 66 (tile 4, ln==2); broadcast within quarter via shfl
    float rinv[4];
    #pragma unroll
    for (int r = 0; r < 4; ++r) {
        float rs = __shfl(acc[4][r], (lane & 48) + 2);
        rinv[r] = 1.0f / (1.0f + rs);
    }

    #pragma unroll
    for (int n0t = 0; n0t < 5; ++n0t) {
        int c = n0t*16 + ln;
        if (c < CIN) {
            #pragma unroll
            for (int r = 0; r < 4; ++r) {
                int gr = row16 + lq*4 + r;
                size_t rowG = (size_t)b*NN + gr;
                float xr = loadX<MODE>(x, state, zr, b, gr, c);
                A[rowG*KP + c]      = f2b(xr);
                A[rowG*KP + 66 + c] = f2b((acc[n0t][r] + xr) * rinv[r]);
            }
        }
    }
    for (int i = t; i < 64*28; i += 256) {
        int rr = i / 28, cc = 132 + (i - 28*(i/28));
        A[((size_t)b*NN + rbase + rr)*KP + cc] = 0;
    }
}

// ---------------------------------------------------------------------------
// K_GEMM v3: B resident in LDS (staged once, ONE barrier), then NT row-tiles
// with A-frags / ne2 / bias direct from global — no further barriers.
//   cc = d*16+oo ordering -> C-tile ct == d; in-register d-contraction
//   epilogue fused with sigmoid (gate) / tanh+GRU combine (upd).
// ---------------------------------------------------------------------------
template<int O, int MODE, int NT>
__global__ __launch_bounds__(256) void k_gemm(
    const unsigned short* __restrict__ A, const unsigned short* __restrict__ BcT,
    const float* __restrict__ ne2, const float* __restrict__ bias_pool,
    const float* __restrict__ state, float* __restrict__ zr,
    float* __restrict__ out)
{
    __shared__ unsigned short s_b[160*168];    // 53.8 KB, resident

    int t = threadIdx.x;
    int w = t >> 6, lane = t & 63, lq = lane >> 4, ln = lane & 15;
    int o0 = blockIdx.y*16;

    for (int i = t; i < 3200; i += 256) {      // stage B once
        int cc = i / 20, kc = i - cc*20;
        int d = cc >> 4, oo = cc & 15;
        *(uint4*)&s_b[cc*168 + kc*8] =
            *(const uint4*)&BcT[(size_t)(d*O + o0 + oo)*KP + kc*8];
    }
    __syncthreads();                            // the only barrier

    int o = o0 + ln;
    float bias[ED];
    #pragma unroll
    for (int d = 0; d < ED; ++d) bias[d] = bias_pool[(size_t)d*O + o];

    for (int tile = 0; tile < NT; ++tile) {
        int rowStart = (blockIdx.x*NT + tile)*64;
        int rowW = rowStart + 16*w;

        f32x4 acc[10];
        #pragma unroll
        for (int i = 0; i < 10; ++i) acc[i] = (f32x4){0.f,0.f,0.f,0.f};

        #pragma unroll
        for (int kc = 0; kc < 5; ++kc) {
            bf16x8 af = *(const bf16x8*)&A[(size_t)(rowW + ln)*KP + kc*32 + lq*8];
            #pragma unroll
            for (int ct = 0; ct < 10; ++ct) {
                bf16x8 bf = *(const bf16x8*)&s_b[(ct*16 + ln)*168 + kc*32 + lq*8];
                acc[ct] = __builtin_amdgcn_mfma_f32_16x16x32_bf16(af, bf, acc[ct], 0, 0, 0);
            }
        }

        #pragma unroll
        for (int r = 0; r < 4; ++r) {
            int row_l = 16*w + lq*4 + r;
            size_t rowG = (size_t)rowStart + row_l;
            int n = (int)(rowG & (NN - 1));
            float val = 0.f;
            #pragma unroll
            for (int d = 0; d < ED; ++d)
                val += ne2[(size_t)n*ED + d] * (acc[d][r] + bias[d]);
            if (MODE == 0) {
                zr[rowG*OG + o] = 1.f/(1.f + __expf(-val));
            } else {
                float hc = tanhf(val);
                float st = state[rowG*OU + o];
                float rg = zr[rowG*OG + OU + o];
                out[rowG*OU + o] = rg*st + (1.f - rg)*hc;
            }
        }
    }
}

// ---------------------------------------------------------------------------
extern "C" void kernel_launch(void* const* d_in, const int* in_sizes, int n_in,
                              void* d_out, int out_size, void* d_ws, size_t ws_size,
                              hipStream_t stream)
{
    const float* x      = (const float*)d_in[0];
    const float* state  = (const float*)d_in[1];
    const float* ne0    = (const float*)d_in[2];
    const float* ne1    = (const float*)d_in[3];
    const float* ne2    = (const float*)d_in[4];
    const float* f1w1   = (const float*)d_in[5];
    const float* f1b1   = (const float*)d_in[6];
    const float* f1w2   = (const float*)d_in[7];
    const float* f1b2   = (const float*)d_in[8];
    const float* f1w3   = (const float*)d_in[9];
    const float* f1b3   = (const float*)d_in[10];
    const float* f2w1   = (const float*)d_in[11];
    const float* f2b1   = (const float*)d_in[12];
    const float* f2w2   = (const float*)d_in[13];
    const float* f2b2   = (const float*)d_in[14];
    const float* f2w3   = (const float*)d_in[15];
    const float* f2b3   = (const float*)d_in[16];
    const float* gate_w = (const float*)d_in[17];
    const float* gate_b = (const float*)d_in[18];
    const float* upd_w  = (const float*)d_in[19];
    const float* upd_b  = (const float*)d_in[20];

    unsigned short* nv1b = (unsigned short*)d_ws;
    unsigned short* nv2b = nv1b + (size_t)BB*NN*TD;
    unsigned short* XTg  = nv2b + (size_t)BB*NN*TD;
    unsigned short* A    = XTg  + (size_t)BB*XTR*NN;
    unsigned short* BcTg = A    + (size_t)BB*NN*KP;
    unsigned short* BcTu = BcTg + (size_t)1280*KP;
    float* zr = (float*)(BcTu + (size_t)640*KP);
    float* out = (float*)d_out;

    k_nv<<<dim3(BB*NN/256), 256, 0, stream>>>(x, state, ne0, ne1,
        f1w1, f1b1, f1w2, f1b2, f1w3, f1b3,
        f2w1, f2b1, f2w2, f2b2, f2w3, f2b3, nv1b, nv2b);

    k_bc<<<dim3(1920*KP/256), 256, 0, stream>>>(gate_w, upd_w, BcTg, BcTu);

    k_xt<0><<<dim3(NN/64, BB), 256, 0, stream>>>(x, state, nullptr, XTg);

    k_aapply<0><<<dim3(NN/64, BB), 256, 0, stream>>>(nv1b, nv2b, XTg,
                                                     x, state, nullptr, A);

    k_gemm<OG,0,4><<<dim3(BB*NN/64/4, 8), 256, 0, stream>>>(A, BcTg, ne2, gate_b,
                                                            nullptr, zr, nullptr);

    k_xt<1><<<dim3(NN/64, BB), 256, 0, stream>>>(x, state, zr, XTg);

    k_aapply<1><<<dim3(NN/64, BB), 256, 0, stream>>>(nv1b, nv2b, XTg,
                                                     x, state, zr, A);

    k_gemm<OU,1,4><<<dim3(BB*NN/64/4, 4), 256, 0, stream>>>(A, BcTu, ne2, upd_b,
                                                            state, zr, out);
}

// Round 6
// 273.248 us; speedup vs baseline: 1.2191x; 1.2191x over previous
//
#include <hip/hip_runtime.h>
#include <math.h>

#define BB   32      // batch
#define NN   1024    // nodes
#define DIN  2
#define DOUT 64
#define CIN  66      // DIN + DOUT
#define TD   32
#define ED   10
#define OG   128     // 2*DOUT (gate out)
#define OU   64      // upd out
#define KP   160     // padded K for the einsum GEMM (132 real)
#define XTR  80      // XT rows per batch (68 data + 12 zero pad)

typedef __bf16 bf16x8 __attribute__((ext_vector_type(8)));
typedef float  f32x4  __attribute__((ext_vector_type(4)));
typedef short  s16x8  __attribute__((ext_vector_type(8)));

__device__ __forceinline__ unsigned short f2b(float f) {
    __bf16 h = (__bf16)f;
    return *(unsigned short*)&h;
}

// ---------------------------------------------------------------------------
// K_PRE: heterogeneous preprocessing, one dispatch.
//   blocks [0,128):    nv MLPs -> nv1b, nv2b (bf16)
//   blocks [128,640):  XT0 build (all 80 rows) + XT1 static rows (0,1,66..79)
//   blocks [640,1840): BcT combined weights (bf16, K-transposed)
//   blocks [1840,2608): biasP precompute: biasG[n][o], biasU[n][o]
// ---------------------------------------------------------------------------
__global__ __launch_bounds__(256) void k_pre(
    const float* __restrict__ x, const float* __restrict__ state,
    const float* __restrict__ ne0, const float* __restrict__ ne1,
    const float* __restrict__ ne2,
    const float* __restrict__ w11, const float* __restrict__ b11,
    const float* __restrict__ w12, const float* __restrict__ b12,
    const float* __restrict__ w13, const float* __restrict__ b13,
    const float* __restrict__ w21, const float* __restrict__ b21,
    const float* __restrict__ w22, const float* __restrict__ b22,
    const float* __restrict__ w23, const float* __restrict__ b23,
    const float* __restrict__ gate_w, const float* __restrict__ gate_b,
    const float* __restrict__ upd_w, const float* __restrict__ upd_b,
    unsigned short* __restrict__ nv1b, unsigned short* __restrict__ nv2b,
    unsigned short* __restrict__ XT0, unsigned short* __restrict__ XT1,
    unsigned short* __restrict__ BcTg, unsigned short* __restrict__ BcTu,
    float* __restrict__ biasG, float* __restrict__ biasU)
{
    __shared__ float sw[2408];
    __shared__ unsigned short st[68*72];
    int blk = blockIdx.x;
    int t = threadIdx.x;

    if (blk < 128) {
        // ---------------- nv job ----------------
        const int oW1 = 0, oB1 = 1056, oW2 = 1072, oB2 = 1104, oW3 = 1108, oB3 = 1172, F2 = 1204;
        for (int i = t; i < 1056; i += 256) { sw[oW1+i] = w11[i]; sw[F2+oW1+i] = w21[i]; }
        if (t < 16) { sw[oB1+t] = b11[t]; sw[F2+oB1+t] = b21[t]; }
        if (t < 32) { sw[oW2+t] = w12[t]; sw[F2+oW2+t] = w22[t]; }
        if (t < 2)  { sw[oB2+t] = b12[t]; sw[F2+oB2+t] = b22[t]; }
        if (t < 64) { sw[oW3+t] = w13[t]; sw[F2+oW3+t] = w23[t]; }
        if (t >= 64 && t < 96) { sw[oB3+t-64] = b13[t-64]; sw[F2+oB3+t-64] = b23[t-64]; }
        __syncthreads();

        int p = blk*256 + t;
        int b = p >> 10;

        float h1a[16], h1b[16];
        #pragma unroll
        for (int j = 0; j < 16; ++j) { h1a[j] = sw[oB1+j]; h1b[j] = sw[F2+oB1+j]; }
        for (int i = 0; i < CIN; ++i) {
            float v = (i < DIN) ? x[(size_t)p*DIN + i] : state[(size_t)p*DOUT + (i-DIN)];
            #pragma unroll
            for (int jq = 0; jq < 4; ++jq) {
                float4 wa = *(const float4*)&sw[oW1 + i*16 + jq*4];
                float4 wb = *(const float4*)&sw[F2 + oW1 + i*16 + jq*4];
                h1a[jq*4+0] += v*wa.x; h1a[jq*4+1] += v*wa.y;
                h1a[jq*4+2] += v*wa.z; h1a[jq*4+3] += v*wa.w;
                h1b[jq*4+0] += v*wb.x; h1b[jq*4+1] += v*wb.y;
                h1b[jq*4+2] += v*wb.z; h1b[jq*4+3] += v*wb.w;
            }
        }
        #pragma unroll
        for (int j = 0; j < 16; ++j) {
            h1a[j] = 1.f/(1.f + __expf(-h1a[j]));
            h1b[j] = 1.f/(1.f + __expf(-h1b[j]));
        }
        float h2a0 = sw[oB2+0], h2a1 = sw[oB2+1];
        float h2b0 = sw[F2+oB2+0], h2b1 = sw[F2+oB2+1];
        #pragma unroll
        for (int i = 0; i < 16; ++i) {
            h2a0 += h1a[i]*sw[oW2 + i*2 + 0];
            h2a1 += h1a[i]*sw[oW2 + i*2 + 1];
            h2b0 += h1b[i]*sw[F2+oW2 + i*2 + 0];
            h2b1 += h1b[i]*sw[F2+oW2 + i*2 + 1];
        }
        h2a0 = 1.f/(1.f + __expf(-h2a0)); h2a1 = 1.f/(1.f + __expf(-h2a1));
        h2b0 = 1.f/(1.f + __expf(-h2b0)); h2b1 = 1.f/(1.f + __expf(-h2b1));

        const float* pn0 = ne0 + b*TD;
        const float* pn1 = ne1 + b*TD;
        #pragma unroll
        for (int jq = 0; jq < 8; ++jq) {
            float4 ba  = *(const float4*)&sw[oB3 + jq*4];
            float4 wa0 = *(const float4*)&sw[oW3 + jq*4];
            float4 wa1 = *(const float4*)&sw[oW3 + 32 + jq*4];
            float4 bb2 = *(const float4*)&sw[F2+oB3 + jq*4];
            float4 wb0 = *(const float4*)&sw[F2+oW3 + jq*4];
            float4 wb1 = *(const float4*)&sw[F2+oW3 + 32 + jq*4];
            float4 n0 = *(const float4*)&pn0[jq*4];
            float4 n1 = *(const float4*)&pn1[jq*4];
            ushort4 u1, u2;
            u1.x = f2b(tanhf(n0.x*(ba.x + h2a0*wa0.x + h2a1*wa1.x)));
            u1.y = f2b(tanhf(n0.y*(ba.y + h2a0*wa0.y + h2a1*wa1.y)));
            u1.z = f2b(tanhf(n0.z*(ba.z + h2a0*wa0.z + h2a1*wa1.z)));
            u1.w = f2b(tanhf(n0.w*(ba.w + h2a0*wa0.w + h2a1*wa1.w)));
            u2.x = f2b(tanhf(n1.x*(bb2.x + h2b0*wb0.x + h2b1*wb1.x)));
            u2.y = f2b(tanhf(n1.y*(bb2.y + h2b0*wb0.y + h2b1*wb1.y)));
            u2.z = f2b(tanhf(n1.z*(bb2.z + h2b0*wb0.z + h2b1*wb1.z)));
            u2.w = f2b(tanhf(n1.w*(bb2.w + h2b0*wb0.w + h2b1*wb1.w)));
            *(ushort4*)&nv1b[(size_t)p*TD + jq*4] = u1;
            *(ushort4*)&nv2b[(size_t)p*TD + jq*4] = u2;
        }
    } else if (blk < 640) {
        // ---------------- XT job ----------------
        int idx = blk - 128;
        int b = idx >> 4, m0 = (idx & 15)*64;
        for (int i = t; i < 1024; i += 256) {
            int m = i >> 4, cq = i & 15;
            size_t base = (size_t)b*NN + m0 + m;
            float4 v = *(const float4*)&state[base*DOUT + cq*4];
            st[(2 + cq*4 + 0)*72 + m] = f2b(v.x);
            st[(2 + cq*4 + 1)*72 + m] = f2b(v.y);
            st[(2 + cq*4 + 2)*72 + m] = f2b(v.z);
            st[(2 + cq*4 + 3)*72 + m] = f2b(v.w);
        }
        if (t < 128) {
            int m = t >> 1, c = t & 1;
            st[c*72 + m] = f2b(x[((size_t)b*NN + m0 + m)*DIN + c]);
        }
        __syncthreads();
        const unsigned int ONE2 = 0x3F803F80u;
        for (int i = t; i < XTR*8; i += 256) {
            int c = i >> 3, ch = i & 7;
            uint4 v;
            if (c < 66)      v = *(const uint4*)&st[c*72 + ch*8];
            else if (c == 66) v = make_uint4(ONE2, ONE2, ONE2, ONE2);
            else              v = make_uint4(0, 0, 0, 0);
            *(uint4*)&XT0[((size_t)b*XTR + c)*NN + m0 + ch*8] = v;
            // XT1 statics: rows 0,1 (x), 66 (ones), 67..79 (zeros); 2..65 by gate
            if (c < 2 || c >= 66)
                *(uint4*)&XT1[((size_t)b*XTR + c)*NN + m0 + ch*8] = v;
        }
    } else if (blk < 1840) {
        // ---------------- BcT job ----------------
        int tid = (blk - 640)*256 + t;            // < 1920*160
        int c = tid / KP, k = tid - c*KP;
        const float* pool; int O, cc; unsigned short* dst;
        if (c < 1280) { pool = gate_w; O = OG; cc = c;        dst = BcTg; }
        else          { pool = upd_w;  O = OU; cc = c - 1280; dst = BcTu; }
        int d = cc / O, o = cc - d*O;
        float v = 0.f;
        if (k < 132) {
            int kp = (k < 66) ? 0 : 1;
            int i  = (k < 66) ? k : k - 66;
            v = pool[(size_t)((d*4 + kp)*CIN + i)*O + o]
              + pool[(size_t)((d*4 + kp + 2)*CIN + i)*O + o];
        }
        dst[(size_t)cc*KP + k] = f2b(v);
    } else {
        // ---------------- bias precompute job ----------------
        int i = (blk - 1840)*256 + t;             // < 1024*192
        int n = i / 192, j = i - n*192;
        float v = 0.f;
        if (j < 128) {
            #pragma unroll
            for (int d = 0; d < ED; ++d) v += ne2[(size_t)n*ED + d]*gate_b[d*OG + j];
            biasG[(size_t)n*OG + j] = v;
        } else {
            int o = j - 128;
            #pragma unroll
            for (int d = 0; d < ED; ++d) v += ne2[(size_t)n*ED + d]*upd_b[d*OU + o];
            biasU[(size_t)n*OU + o] = v;
        }
    }
}

// ---------------------------------------------------------------------------
// K_AAPPLY (R2-proven structure): 64 rows x one batch per block, cooperative
// staging, 2 barriers/iter. Emits GEMM A rows bf16:
//   A[row][0..65]=X (bit-copy from XT), A[row][66..131]=(relu(adj)@X+X)/(1+rs),
//   A[row][132..159]=0.
// ---------------------------------------------------------------------------
__global__ __launch_bounds__(256) void k_aapply(
    const unsigned short* __restrict__ nv1b, const unsigned short* __restrict__ nv2b,
    const unsigned short* __restrict__ XTg, unsigned short* __restrict__ A)
{
    __shared__ unsigned short s_nv1r[64*40], s_nv2r[64*40];
    __shared__ unsigned short s_nv1c[64*40], s_nv2c[64*40];
    __shared__ unsigned short s_p[64*72];
    __shared__ unsigned short s_xt[80*72];
    __shared__ float s_rs[64];

    int t = threadIdx.x;
    int b = blockIdx.y, rbase = blockIdx.x*64;
    int w = t >> 6, lane = t & 63, lq = lane >> 4, ln = lane & 15;

    for (int i = t; i < 512; i += 256) {
        int arr = i >> 8, j = i & 255;
        int node = j >> 2, ch = j & 3;
        const unsigned short* src = (arr ? nv2b : nv1b)
            + ((size_t)b*NN + rbase + node)*TD + ch*8;
        unsigned short* dst = (arr ? s_nv2r : s_nv1r) + node*40 + ch*8;
        *(uint4*)dst = *(const uint4*)src;
    }
    __syncthreads();

    bf16x8 a1 = *(const bf16x8*)&s_nv1r[(16*w + ln)*40 + lq*8];
    s16x8 a2s = *(const s16x8*)&s_nv2r[(16*w + ln)*40 + lq*8];
    const s16x8 sgn = {(short)0x8000,(short)0x8000,(short)0x8000,(short)0x8000,
                       (short)0x8000,(short)0x8000,(short)0x8000,(short)0x8000};
    a2s ^= sgn;
    bf16x8 a2n = (bf16x8)a2s;

    f32x4 acc[5];
    #pragma unroll
    for (int i = 0; i < 5; ++i) acc[i] = (f32x4){0.f,0.f,0.f,0.f};
    const f32x4 zero4 = {0.f,0.f,0.f,0.f};

    for (int mb = 0; mb < NN; mb += 64) {
        __syncthreads();
        for (int i = t; i < 512; i += 256) {
            int arr = i >> 8, j = i & 255;
            int node = j >> 2, ch = j & 3;
            const unsigned short* src = (arr ? nv2b : nv1b)
                + ((size_t)b*NN + mb + node)*TD + ch*8;
            unsigned short* dst = (arr ? s_nv2c : s_nv1c) + node*40 + ch*8;
            *(uint4*)dst = *(const uint4*)src;
        }
        for (int i = t; i < 640; i += 256) {        // all 80 XT rows (pad in global)
            int c = i >> 3, ch = i & 7;
            *(uint4*)&s_xt[c*72 + ch*8] =
                *(const uint4*)&XTg[((size_t)b*XTR + c)*NN + mb + ch*8];
        }
        __syncthreads();

        #pragma unroll
        for (int j0t = 0; j0t < 4; ++j0t) {
            int j0 = j0t*16;
            bf16x8 b2 = *(const bf16x8*)&s_nv2c[(j0 + ln)*40 + lq*8];
            bf16x8 b1 = *(const bf16x8*)&s_nv1c[(j0 + ln)*40 + lq*8];
            f32x4 s = __builtin_amdgcn_mfma_f32_16x16x32_bf16(a1,  b2, zero4, 0, 0, 0);
            s       = __builtin_amdgcn_mfma_f32_16x16x32_bf16(a2n, b1, s,     0, 0, 0);
            #pragma unroll
            for (int r = 0; r < 4; ++r) {
                float p = fmaxf(s[r], 0.f);
                *(__bf16*)&s_p[(16*w + lq*4 + r)*72 + j0 + ln] = (__bf16)p;
            }
        }

        bf16x8 pa0 = *(const bf16x8*)&s_p[(16*w + ln)*72 +      lq*8];
        bf16x8 pa1 = *(const bf16x8*)&s_p[(16*w + ln)*72 + 32 + lq*8];
        #pragma unroll
        for (int n0t = 0; n0t < 5; ++n0t) {
            int n0 = n0t*16;
            bf16x8 xb0 = *(const bf16x8*)&s_xt[(n0 + ln)*72 +      lq*8];
            bf16x8 xb1 = *(const bf16x8*)&s_xt[(n0 + ln)*72 + 32 + lq*8];
            acc[n0t] = __builtin_amdgcn_mfma_f32_16x16x32_bf16(pa0, xb0, acc[n0t], 0, 0, 0);
            acc[n0t] = __builtin_amdgcn_mfma_f32_16x16x32_bf16(pa1, xb1, acc[n0t], 0, 0, 0);
        }
    }

    if (ln == 2) {
        #pragma unroll
        for (int r = 0; r < 4; ++r) s_rs[16*w + lq*4 + r] = acc[4][r];
    }
    float rinv[4];
    #pragma unroll
    for (int r = 0; r < 4; ++r) rinv[r] = 1.0f / (1.0f + s_rs[16*w + lq*4 + r]);

    #pragma unroll
    for (int n0t = 0; n0t < 5; ++n0t) {
        int c = n0t*16 + ln;
        if (c < CIN) {
            #pragma unroll
            for (int r = 0; r < 4; ++r) {
                int gr = rbase + 16*w + lq*4 + r;
                size_t rowG = (size_t)b*NN + gr;
                unsigned short xu = XTg[((size_t)b*XTR + c)*NN + gr];
                float xr = (float)(*(const __bf16*)&xu);
                A[rowG*KP + c]      = xu;
                A[rowG*KP + 66 + c] = f2b((acc[n0t][r] + xr) * rinv[r]);
            }
        }
    }
    for (int i = t; i < 64*28; i += 256) {
        int rr = i / 28, cc = 132 + (i - 28*(i/28));
        A[((size_t)b*NN + rbase + rr)*KP + cc] = 0;
    }
}

// ---------------------------------------------------------------------------
// K_GEMM v4: wave = 32 rows x 160 cols (10 d x 16 o). B resident in LDS
// (single barrier); A-frags direct from global; each B-frag read feeds 2 MFMA.
// Epilogue: in-register d-contraction + precomputed bias.
//   MODE 0, o<64:  XT1[b][2+o][n] = bf16(sigmoid(val)*state)   (z-path)
//   MODE 0, o>=64: rbuf[row][o-64] = sigmoid(val)              (r-path)
//   MODE 1:        out = r*state + (1-r)*tanh(val)
// ---------------------------------------------------------------------------
template<int O, int MODE>
__global__ __launch_bounds__(256) void k_gemm(
    const unsigned short* __restrict__ A, const unsigned short* __restrict__ BcT,
    const float* __restrict__ ne2, const float* __restrict__ biasP,
    const float* __restrict__ state, unsigned short* __restrict__ XT1,
    float* __restrict__ rbuf, float* __restrict__ out)
{
    __shared__ unsigned short s_b[160*168];    // 53.8 KB
    __shared__ float s_ne[128*16];             // 8 KB

    int t = threadIdx.x;
    int w = t >> 6, lane = t & 63, lq = lane >> 4, ln = lane & 15;
    int o0 = blockIdx.y*16;
    int rowBlock = blockIdx.x*128;

    for (int i = t; i < 3200; i += 256) {
        int cc = i / 20, kc = i - cc*20;
        int d = cc >> 4, oo = cc & 15;
        *(uint4*)&s_b[cc*168 + kc*8] =
            *(const uint4*)&BcT[(size_t)(d*O + o0 + oo)*KP + kc*8];
    }
    for (int i = t; i < 1280; i += 256) {
        int r = i / 10, d = i - r*10;
        int n = (rowBlock + r) & (NN - 1);
        s_ne[r*16 + d] = ne2[(size_t)n*ED + d];
    }
    __syncthreads();                            // the only barrier

    int rowW = rowBlock + w*32;
    f32x4 acc0[10], acc1[10];
    #pragma unroll
    for (int i = 0; i < 10; ++i) {
        acc0[i] = (f32x4){0.f,0.f,0.f,0.f};
        acc1[i] = (f32x4){0.f,0.f,0.f,0.f};
    }

    #pragma unroll
    for (int kc = 0; kc < 5; ++kc) {
        bf16x8 af0 = *(const bf16x8*)&A[(size_t)(rowW      + ln)*KP + kc*32 + lq*8];
        bf16x8 af1 = *(const bf16x8*)&A[(size_t)(rowW + 16 + ln)*KP + kc*32 + lq*8];
        #pragma unroll
        for (int ct = 0; ct < 10; ++ct) {
            bf16x8 bf = *(const bf16x8*)&s_b[(ct*16 + ln)*168 + kc*32 + lq*8];
            acc0[ct] = __builtin_amdgcn_mfma_f32_16x16x32_bf16(af0, bf, acc0[ct], 0, 0, 0);
            acc1[ct] = __builtin_amdgcn_mfma_f32_16x16x32_bf16(af1, bf, acc1[ct], 0, 0, 0);
        }
    }

    int o = o0 + ln;
    #pragma unroll
    for (int f = 0; f < 2; ++f) {
        #pragma unroll
        for (int r = 0; r < 4; ++r) {
            int row_l = w*32 + 16*f + lq*4 + r;
            size_t rowG = (size_t)rowBlock + row_l;
            int n = (int)(rowG & (NN - 1));
            int bb = (int)(rowG >> 10);
            f32x4 nA = *(const f32x4*)&s_ne[row_l*16];
            f32x4 nB = *(const f32x4*)&s_ne[row_l*16 + 4];
            float n8 = s_ne[row_l*16 + 8], n9 = s_ne[row_l*16 + 9];
            float val = biasP[(size_t)n*O + o];
            if (f == 0) {
                val += nA.x*acc0[0][r] + nA.y*acc0[1][r] + nA.z*acc0[2][r] + nA.w*acc0[3][r]
                     + nB.x*acc0[4][r] + nB.y*acc0[5][r] + nB.z*acc0[6][r] + nB.w*acc0[7][r]
                     + n8*acc0[8][r] + n9*acc0[9][r];
            } else {
                val += nA.x*acc1[0][r] + nA.y*acc1[1][r] + nA.z*acc1[2][r] + nA.w*acc1[3][r]
                     + nB.x*acc1[4][r] + nB.y*acc1[5][r] + nB.z*acc1[6][r] + nB.w*acc1[7][r]
                     + n8*acc1[8][r] + n9*acc1[9][r];
            }
            if (MODE == 0) {
                float sv = 1.f/(1.f + __expf(-val));
                if (o0 < 64) {
                    float zst = sv * state[rowG*DOUT + o];
                    XT1[((size_t)bb*XTR + 2 + o)*NN + n] = f2b(zst);
                } else {
                    rbuf[rowG*DOUT + (o - 64)] = sv;
                }
            } else {
                float hc = tanhf(val);
                float rg = rbuf[rowG*DOUT + o];
                float st = state[rowG*DOUT + o];
                out[rowG*DOUT + o] = rg*st + (1.f - rg)*hc;
            }
        }
    }
}

// ---------------------------------------------------------------------------
extern "C" void kernel_launch(void* const* d_in, const int* in_sizes, int n_in,
                              void* d_out, int out_size, void* d_ws, size_t ws_size,
                              hipStream_t stream)
{
    const float* x      = (const float*)d_in[0];
    const float* state  = (const float*)d_in[1];
    const float* ne0    = (const float*)d_in[2];
    const float* ne1    = (const float*)d_in[3];
    const float* ne2    = (const float*)d_in[4];
    const float* f1w1   = (const float*)d_in[5];
    const float* f1b1   = (const float*)d_in[6];
    const float* f1w2   = (const float*)d_in[7];
    const float* f1b2   = (const float*)d_in[8];
    const float* f1w3   = (const float*)d_in[9];
    const float* f1b3   = (const float*)d_in[10];
    const float* f2w1   = (const float*)d_in[11];
    const float* f2b1   = (const float*)d_in[12];
    const float* f2w2   = (const float*)d_in[13];
    const float* f2b2   = (const float*)d_in[14];
    const float* f2w3   = (const float*)d_in[15];
    const float* f2b3   = (const float*)d_in[16];
    const float* gate_w = (const float*)d_in[17];
    const float* gate_b = (const float*)d_in[18];
    const float* upd_w  = (const float*)d_in[19];
    const float* upd_b  = (const float*)d_in[20];

    // ws layout: nv1b 2M | nv2b 2M | XT0 5.24M | XT1 5.24M | A 10.5M |
    // BcTg 0.41M | BcTu 0.2M | biasG 0.5M | biasU 0.25M | rbuf 8.4M  ~35MB
    unsigned short* nv1b = (unsigned short*)d_ws;
    unsigned short* nv2b = nv1b + (size_t)BB*NN*TD;
    unsigned short* XT0  = nv2b + (size_t)BB*NN*TD;
    unsigned short* XT1  = XT0  + (size_t)BB*XTR*NN;
    unsigned short* A    = XT1  + (size_t)BB*XTR*NN;
    unsigned short* BcTg = A    + (size_t)BB*NN*KP;
    unsigned short* BcTu = BcTg + (size_t)1280*KP;
    float* biasG = (float*)(BcTu + (size_t)640*KP);
    float* biasU = biasG + (size_t)NN*OG;
    float* rbuf  = biasU + (size_t)NN*OU;
    float* out   = (float*)d_out;

    k_pre<<<dim3(2608), 256, 0, stream>>>(x, state, ne0, ne1, ne2,
        f1w1, f1b1, f1w2, f1b2, f1w3, f1b3,
        f2w1, f2b1, f2w2, f2b2, f2w3, f2b3,
        gate_w, gate_b, upd_w, upd_b,
        nv1b, nv2b, XT0, XT1, BcTg, BcTu, biasG, biasU);

    k_aapply<<<dim3(NN/64, BB), 256, 0, stream>>>(nv1b, nv2b, XT0, A);

    k_gemm<OG,0><<<dim3(BB*NN/128, 8), 256, 0, stream>>>(A, BcTg, ne2, biasG,
                                                         state, XT1, rbuf, nullptr);

    k_aapply<<<dim3(NN/64, BB), 256, 0, stream>>>(nv1b, nv2b, XT1, A);

    k_gemm<OU,1><<<dim3(BB*NN/128, 4), 256, 0, stream>>>(A, BcTu, ne2, biasU,
                                                         state, nullptr, rbuf, out);
}

// Round 7
// 254.973 us; speedup vs baseline: 1.3064x; 1.0717x over previous
//
#include <hip/hip_runtime.h>
#include <math.h>

#define BB   32      // batch
#define NN   1024    // nodes
#define DIN  2
#define DOUT 64
#define CIN  66      // DIN + DOUT
#define TD   32
#define ED   10
#define OG   128     // 2*DOUT (gate out)
#define OU   64      // upd out
#define KP   160     // padded K for the einsum GEMM (132 real)
#define XTR  80      // XT rows per batch (68 data + 12 zero pad)
#define PS   88      // s_p stride (shorts): 16B-aligned, 2-way banks only

typedef __bf16 bf16x8 __attribute__((ext_vector_type(8)));
typedef float  f32x4  __attribute__((ext_vector_type(4)));
typedef short  s16x8  __attribute__((ext_vector_type(8)));

__device__ __forceinline__ unsigned short f2b(float f) {
    __bf16 h = (__bf16)f;
    return *(unsigned short*)&h;
}

// ---------------------------------------------------------------------------
// K_PRE: heterogeneous preprocessing, one dispatch.
//   blocks [0,128):    nv MLPs -> nv1b, nv2b (bf16)
//   blocks [128,640):  XT0 build (all 80 rows) + XT1 static rows (0,1,66..79)
//   blocks [640,1840): BcT combined weights (bf16, K-transposed)
//   blocks [1840,2608): biasP precompute: biasG[n][o], biasU[n][o]
// ---------------------------------------------------------------------------
__global__ __launch_bounds__(256) void k_pre(
    const float* __restrict__ x, const float* __restrict__ state,
    const float* __restrict__ ne0, const float* __restrict__ ne1,
    const float* __restrict__ ne2,
    const float* __restrict__ w11, const float* __restrict__ b11,
    const float* __restrict__ w12, const float* __restrict__ b12,
    const float* __restrict__ w13, const float* __restrict__ b13,
    const float* __restrict__ w21, const float* __restrict__ b21,
    const float* __restrict__ w22, const float* __restrict__ b22,
    const float* __restrict__ w23, const float* __restrict__ b23,
    const float* __restrict__ gate_w, const float* __restrict__ gate_b,
    const float* __restrict__ upd_w, const float* __restrict__ upd_b,
    unsigned short* __restrict__ nv1b, unsigned short* __restrict__ nv2b,
    unsigned short* __restrict__ XT0, unsigned short* __restrict__ XT1,
    unsigned short* __restrict__ BcTg, unsigned short* __restrict__ BcTu,
    float* __restrict__ biasG, float* __restrict__ biasU)
{
    __shared__ float sw[2408];
    __shared__ unsigned short st[68*72];
    int blk = blockIdx.x;
    int t = threadIdx.x;

    if (blk < 128) {
        const int oW1 = 0, oB1 = 1056, oW2 = 1072, oB2 = 1104, oW3 = 1108, oB3 = 1172, F2 = 1204;
        for (int i = t; i < 1056; i += 256) { sw[oW1+i] = w11[i]; sw[F2+oW1+i] = w21[i]; }
        if (t < 16) { sw[oB1+t] = b11[t]; sw[F2+oB1+t] = b21[t]; }
        if (t < 32) { sw[oW2+t] = w12[t]; sw[F2+oW2+t] = w22[t]; }
        if (t < 2)  { sw[oB2+t] = b12[t]; sw[F2+oB2+t] = b22[t]; }
        if (t < 64) { sw[oW3+t] = w13[t]; sw[F2+oW3+t] = w23[t]; }
        if (t >= 64 && t < 96) { sw[oB3+t-64] = b13[t-64]; sw[F2+oB3+t-64] = b23[t-64]; }
        __syncthreads();

        int p = blk*256 + t;
        int b = p >> 10;

        float h1a[16], h1b[16];
        #pragma unroll
        for (int j = 0; j < 16; ++j) { h1a[j] = sw[oB1+j]; h1b[j] = sw[F2+oB1+j]; }
        for (int i = 0; i < CIN; ++i) {
            float v = (i < DIN) ? x[(size_t)p*DIN + i] : state[(size_t)p*DOUT + (i-DIN)];
            #pragma unroll
            for (int jq = 0; jq < 4; ++jq) {
                float4 wa = *(const float4*)&sw[oW1 + i*16 + jq*4];
                float4 wb = *(const float4*)&sw[F2 + oW1 + i*16 + jq*4];
                h1a[jq*4+0] += v*wa.x; h1a[jq*4+1] += v*wa.y;
                h1a[jq*4+2] += v*wa.z; h1a[jq*4+3] += v*wa.w;
                h1b[jq*4+0] += v*wb.x; h1b[jq*4+1] += v*wb.y;
                h1b[jq*4+2] += v*wb.z; h1b[jq*4+3] += v*wb.w;
            }
        }
        #pragma unroll
        for (int j = 0; j < 16; ++j) {
            h1a[j] = 1.f/(1.f + __expf(-h1a[j]));
            h1b[j] = 1.f/(1.f + __expf(-h1b[j]));
        }
        float h2a0 = sw[oB2+0], h2a1 = sw[oB2+1];
        float h2b0 = sw[F2+oB2+0], h2b1 = sw[F2+oB2+1];
        #pragma unroll
        for (int i = 0; i < 16; ++i) {
            h2a0 += h1a[i]*sw[oW2 + i*2 + 0];
            h2a1 += h1a[i]*sw[oW2 + i*2 + 1];
            h2b0 += h1b[i]*sw[F2+oW2 + i*2 + 0];
            h2b1 += h1b[i]*sw[F2+oW2 + i*2 + 1];
        }
        h2a0 = 1.f/(1.f + __expf(-h2a0)); h2a1 = 1.f/(1.f + __expf(-h2a1));
        h2b0 = 1.f/(1.f + __expf(-h2b0)); h2b1 = 1.f/(1.f + __expf(-h2b1));

        const float* pn0 = ne0 + b*TD;
        const float* pn1 = ne1 + b*TD;
        #pragma unroll
        for (int jq = 0; jq < 8; ++jq) {
            float4 ba  = *(const float4*)&sw[oB3 + jq*4];
            float4 wa0 = *(const float4*)&sw[oW3 + jq*4];
            float4 wa1 = *(const float4*)&sw[oW3 + 32 + jq*4];
            float4 bb2 = *(const float4*)&sw[F2+oB3 + jq*4];
            float4 wb0 = *(const float4*)&sw[F2+oW3 + jq*4];
            float4 wb1 = *(const float4*)&sw[F2+oW3 + 32 + jq*4];
            float4 n0 = *(const float4*)&pn0[jq*4];
            float4 n1 = *(const float4*)&pn1[jq*4];
            ushort4 u1, u2;
            u1.x = f2b(tanhf(n0.x*(ba.x + h2a0*wa0.x + h2a1*wa1.x)));
            u1.y = f2b(tanhf(n0.y*(ba.y + h2a0*wa0.y + h2a1*wa1.y)));
            u1.z = f2b(tanhf(n0.z*(ba.z + h2a0*wa0.z + h2a1*wa1.z)));
            u1.w = f2b(tanhf(n0.w*(ba.w + h2a0*wa0.w + h2a1*wa1.w)));
            u2.x = f2b(tanhf(n1.x*(bb2.x + h2b0*wb0.x + h2b1*wb1.x)));
            u2.y = f2b(tanhf(n1.y*(bb2.y + h2b0*wb0.y + h2b1*wb1.y)));
            u2.z = f2b(tanhf(n1.z*(bb2.z + h2b0*wb0.z + h2b1*wb1.z)));
            u2.w = f2b(tanhf(n1.w*(bb2.w + h2b0*wb0.w + h2b1*wb1.w)));
            *(ushort4*)&nv1b[(size_t)p*TD + jq*4] = u1;
            *(ushort4*)&nv2b[(size_t)p*TD + jq*4] = u2;
        }
    } else if (blk < 640) {
        int idx = blk - 128;
        int b = idx >> 4, m0 = (idx & 15)*64;
        for (int i = t; i < 1024; i += 256) {
            int m = i >> 4, cq = i & 15;
            size_t base = (size_t)b*NN + m0 + m;
            float4 v = *(const float4*)&state[base*DOUT + cq*4];
            st[(2 + cq*4 + 0)*72 + m] = f2b(v.x);
            st[(2 + cq*4 + 1)*72 + m] = f2b(v.y);
            st[(2 + cq*4 + 2)*72 + m] = f2b(v.z);
            st[(2 + cq*4 + 3)*72 + m] = f2b(v.w);
        }
        if (t < 128) {
            int m = t >> 1, c = t & 1;
            st[c*72 + m] = f2b(x[((size_t)b*NN + m0 + m)*DIN + c]);
        }
        __syncthreads();
        const unsigned int ONE2 = 0x3F803F80u;
        for (int i = t; i < XTR*8; i += 256) {
            int c = i >> 3, ch = i & 7;
            uint4 v;
            if (c < 66)      v = *(const uint4*)&st[c*72 + ch*8];
            else if (c == 66) v = make_uint4(ONE2, ONE2, ONE2, ONE2);
            else              v = make_uint4(0, 0, 0, 0);
            *(uint4*)&XT0[((size_t)b*XTR + c)*NN + m0 + ch*8] = v;
            if (c < 2 || c >= 66)
                *(uint4*)&XT1[((size_t)b*XTR + c)*NN + m0 + ch*8] = v;
        }
    } else if (blk < 1840) {
        int tid = (blk - 640)*256 + t;
        int c = tid / KP, k = tid - c*KP;
        const float* pool; int O, cc; unsigned short* dst;
        if (c < 1280) { pool = gate_w; O = OG; cc = c;        dst = BcTg; }
        else          { pool = upd_w;  O = OU; cc = c - 1280; dst = BcTu; }
        int d = cc / O, o = cc - d*O;
        float v = 0.f;
        if (k < 132) {
            int kp = (k < 66) ? 0 : 1;
            int i  = (k < 66) ? k : k - 66;
            v = pool[(size_t)((d*4 + kp)*CIN + i)*O + o]
              + pool[(size_t)((d*4 + kp + 2)*CIN + i)*O + o];
        }
        dst[(size_t)cc*KP + k] = f2b(v);
    } else {
        int i = (blk - 1840)*256 + t;
        int n = i / 192, j = i - n*192;
        float v = 0.f;
        if (j < 128) {
            #pragma unroll
            for (int d = 0; d < ED; ++d) v += ne2[(size_t)n*ED + d]*gate_b[d*OG + j];
            biasG[(size_t)n*OG + j] = v;
        } else {
            int o = j - 128;
            #pragma unroll
            for (int d = 0; d < ED; ++d) v += ne2[(size_t)n*ED + d]*upd_b[d*OU + o];
            biasU[(size_t)n*OU + o] = v;
        }
    }
}

// ---------------------------------------------------------------------------
// K_AAPPLY: R2-proven cooperative-staging structure + XCD swizzle (batch ->
// fixed XCD: id = rb*32 + b, id%8 == b%8) + s_p stride 88 (conflict-free).
// ---------------------------------------------------------------------------
__global__ __launch_bounds__(256) void k_aapply(
    const unsigned short* __restrict__ nv1b, const unsigned short* __restrict__ nv2b,
    const unsigned short* __restrict__ XTg, unsigned short* __restrict__ A)
{
    __shared__ unsigned short s_nv1r[64*40], s_nv2r[64*40];
    __shared__ unsigned short s_nv1c[64*40], s_nv2c[64*40];
    __shared__ unsigned short s_p[64*PS];
    __shared__ unsigned short s_xt[80*72];
    __shared__ float s_rs[64];

    int t = threadIdx.x;
    int id = blockIdx.x;
    int b = id & 31, rbase = (id >> 5)*64;     // XCD-aligned: all rb of b on XCD b%8
    int w = t >> 6, lane = t & 63, lq = lane >> 4, ln = lane & 15;

    for (int i = t; i < 512; i += 256) {
        int arr = i >> 8, j = i & 255;
        int node = j >> 2, ch = j & 3;
        const unsigned short* src = (arr ? nv2b : nv1b)
            + ((size_t)b*NN + rbase + node)*TD + ch*8;
        unsigned short* dst = (arr ? s_nv2r : s_nv1r) + node*40 + ch*8;
        *(uint4*)dst = *(const uint4*)src;
    }
    __syncthreads();

    bf16x8 a1 = *(const bf16x8*)&s_nv1r[(16*w + ln)*40 + lq*8];
    s16x8 a2s = *(const s16x8*)&s_nv2r[(16*w + ln)*40 + lq*8];
    const s16x8 sgn = {(short)0x8000,(short)0x8000,(short)0x8000,(short)0x8000,
                       (short)0x8000,(short)0x8000,(short)0x8000,(short)0x8000};
    a2s ^= sgn;
    bf16x8 a2n = (bf16x8)a2s;

    f32x4 acc[5];
    #pragma unroll
    for (int i = 0; i < 5; ++i) acc[i] = (f32x4){0.f,0.f,0.f,0.f};
    const f32x4 zero4 = {0.f,0.f,0.f,0.f};

    for (int mb = 0; mb < NN; mb += 64) {
        __syncthreads();
        for (int i = t; i < 512; i += 256) {
            int arr = i >> 8, j = i & 255;
            int node = j >> 2, ch = j & 3;
            const unsigned short* src = (arr ? nv2b : nv1b)
                + ((size_t)b*NN + mb + node)*TD + ch*8;
            unsigned short* dst = (arr ? s_nv2c : s_nv1c) + node*40 + ch*8;
            *(uint4*)dst = *(const uint4*)src;
        }
        for (int i = t; i < 640; i += 256) {
            int c = i >> 3, ch = i & 7;
            *(uint4*)&s_xt[c*72 + ch*8] =
                *(const uint4*)&XTg[((size_t)b*XTR + c)*NN + mb + ch*8];
        }
        __syncthreads();

        #pragma unroll
        for (int j0t = 0; j0t < 4; ++j0t) {
            int j0 = j0t*16;
            bf16x8 b2 = *(const bf16x8*)&s_nv2c[(j0 + ln)*40 + lq*8];
            bf16x8 b1 = *(const bf16x8*)&s_nv1c[(j0 + ln)*40 + lq*8];
            f32x4 s = __builtin_amdgcn_mfma_f32_16x16x32_bf16(a1,  b2, zero4, 0, 0, 0);
            s       = __builtin_amdgcn_mfma_f32_16x16x32_bf16(a2n, b1, s,     0, 0, 0);
            #pragma unroll
            for (int r = 0; r < 4; ++r) {
                float p = fmaxf(s[r], 0.f);
                *(__bf16*)&s_p[(16*w + lq*4 + r)*PS + j0 + ln] = (__bf16)p;
            }
        }

        bf16x8 pa0 = *(const bf16x8*)&s_p[(16*w + ln)*PS +      lq*8];
        bf16x8 pa1 = *(const bf16x8*)&s_p[(16*w + ln)*PS + 32 + lq*8];
        #pragma unroll
        for (int n0t = 0; n0t < 5; ++n0t) {
            int n0 = n0t*16;
            bf16x8 xb0 = *(const bf16x8*)&s_xt[(n0 + ln)*72 +      lq*8];
            bf16x8 xb1 = *(const bf16x8*)&s_xt[(n0 + ln)*72 + 32 + lq*8];
            acc[n0t] = __builtin_amdgcn_mfma_f32_16x16x32_bf16(pa0, xb0, acc[n0t], 0, 0, 0);
            acc[n0t] = __builtin_amdgcn_mfma_f32_16x16x32_bf16(pa1, xb1, acc[n0t], 0, 0, 0);
        }
    }

    if (ln == 2) {
        #pragma unroll
        for (int r = 0; r < 4; ++r) s_rs[16*w + lq*4 + r] = acc[4][r];
    }
    float rinv[4];
    #pragma unroll
    for (int r = 0; r < 4; ++r) rinv[r] = 1.0f / (1.0f + s_rs[16*w + lq*4 + r]);

    #pragma unroll
    for (int n0t = 0; n0t < 5; ++n0t) {
        int c = n0t*16 + ln;
        if (c < CIN) {
            #pragma unroll
            for (int r = 0; r < 4; ++r) {
                int gr = rbase + 16*w + lq*4 + r;
                size_t rowG = (size_t)b*NN + gr;
                unsigned short xu = XTg[((size_t)b*XTR + c)*NN + gr];
                float xr = (float)(*(const __bf16*)&xu);
                A[rowG*KP + c]      = xu;
                A[rowG*KP + 66 + c] = f2b((acc[n0t][r] + xr) * rinv[r]);
            }
        }
    }
    for (int i = t; i < 64*28; i += 256) {
        int rr = i / 28, cc = 132 + (i - 28*(i/28));
        A[((size_t)b*NN + rbase + rr)*KP + cc] = 0;
    }
}

// ---------------------------------------------------------------------------
// K_GEMM v5: half-B resident (5 d's, 26.9 KB) -> 4+ blocks/CU; two halves with
// restage barriers. ne2/bias direct from global (L1-hot) — no s_ne conflicts.
// wave = 32 rows; epilogue in-register d-contraction + fused activation.
// ---------------------------------------------------------------------------
template<int O, int MODE>
__global__ __launch_bounds__(256) void k_gemm(
    const unsigned short* __restrict__ A, const unsigned short* __restrict__ BcT,
    const float* __restrict__ ne2, const float* __restrict__ biasP,
    const float* __restrict__ state, unsigned short* __restrict__ XT1,
    float* __restrict__ rbuf, float* __restrict__ out)
{
    __shared__ unsigned short s_b[80*168];     // 26.9 KB (one d-half)

    int t = threadIdx.x;
    int w = t >> 6, lane = t & 63, lq = lane >> 4, ln = lane & 15;
    int o0 = blockIdx.y*16;
    int rowBlock = blockIdx.x*128;
    int rowW = rowBlock + w*32;

    f32x4 acc[2][2][5];                        // [half][frag][ct] = 80 VGPR
    #pragma unroll
    for (int h = 0; h < 2; ++h)
        #pragma unroll
        for (int f = 0; f < 2; ++f)
            #pragma unroll
            for (int c = 0; c < 5; ++c) acc[h][f][c] = (f32x4){0.f,0.f,0.f,0.f};

    #pragma unroll
    for (int h = 0; h < 2; ++h) {
        if (h) __syncthreads();                // all waves done with half 0
        for (int i = t; i < 1600; i += 256) {  // stage this half's B
            int cc = i / 20, kc = i - cc*20;
            int d = h*5 + (cc >> 4), oo = cc & 15;
            *(uint4*)&s_b[cc*168 + kc*8] =
                *(const uint4*)&BcT[(size_t)(d*O + o0 + oo)*KP + kc*8];
        }
        __syncthreads();

        #pragma unroll
        for (int kc = 0; kc < 5; ++kc) {
            bf16x8 af0 = *(const bf16x8*)&A[(size_t)(rowW      + ln)*KP + kc*32 + lq*8];
            bf16x8 af1 = *(const bf16x8*)&A[(size_t)(rowW + 16 + ln)*KP + kc*32 + lq*8];
            #pragma unroll
            for (int ct = 0; ct < 5; ++ct) {
                bf16x8 bf = *(const bf16x8*)&s_b[(ct*16 + ln)*168 + kc*32 + lq*8];
                acc[h][0][ct] = __builtin_amdgcn_mfma_f32_16x16x32_bf16(af0, bf, acc[h][0][ct], 0, 0, 0);
                acc[h][1][ct] = __builtin_amdgcn_mfma_f32_16x16x32_bf16(af1, bf, acc[h][1][ct], 0, 0, 0);
            }
        }
    }

    int o = o0 + ln;
    #pragma unroll
    for (int f = 0; f < 2; ++f) {
        #pragma unroll
        for (int r = 0; r < 4; ++r) {
            int row_l = w*32 + 16*f + lq*4 + r;
            size_t rowG = (size_t)rowBlock + row_l;
            int n = (int)(rowG & (NN - 1));
            int bb = (int)(rowG >> 10);
            const float* nep = &ne2[(size_t)n*ED];
            float val = biasP[(size_t)n*O + o];
            #pragma unroll
            for (int d = 0; d < 5; ++d) val += nep[d]     * acc[0][f][d][r];
            #pragma unroll
            for (int d = 0; d < 5; ++d) val += nep[5 + d] * acc[1][f][d][r];
            if (MODE == 0) {
                float sv = 1.f/(1.f + __expf(-val));
                if (o0 < 64) {
                    float zst = sv * state[rowG*DOUT + o];
                    XT1[((size_t)bb*XTR + 2 + o)*NN + n] = f2b(zst);
                } else {
                    rbuf[rowG*DOUT + (o - 64)] = sv;
                }
            } else {
                float hc = tanhf(val);
                float rg = rbuf[rowG*DOUT + o];
                float st = state[rowG*DOUT + o];
                out[rowG*DOUT + o] = rg*st + (1.f - rg)*hc;
            }
        }
    }
}

// ---------------------------------------------------------------------------
extern "C" void kernel_launch(void* const* d_in, const int* in_sizes, int n_in,
                              void* d_out, int out_size, void* d_ws, size_t ws_size,
                              hipStream_t stream)
{
    const float* x      = (const float*)d_in[0];
    const float* state  = (const float*)d_in[1];
    const float* ne0    = (const float*)d_in[2];
    const float* ne1    = (const float*)d_in[3];
    const float* ne2    = (const float*)d_in[4];
    const float* f1w1   = (const float*)d_in[5];
    const float* f1b1   = (const float*)d_in[6];
    const float* f1w2   = (const float*)d_in[7];
    const float* f1b2   = (const float*)d_in[8];
    const float* f1w3   = (const float*)d_in[9];
    const float* f1b3   = (const float*)d_in[10];
    const float* f2w1   = (const float*)d_in[11];
    const float* f2b1   = (const float*)d_in[12];
    const float* f2w2   = (const float*)d_in[13];
    const float* f2b2   = (const float*)d_in[14];
    const float* f2w3   = (const float*)d_in[15];
    const float* f2b3   = (const float*)d_in[16];
    const float* gate_w = (const float*)d_in[17];
    const float* gate_b = (const float*)d_in[18];
    const float* upd_w  = (const float*)d_in[19];
    const float* upd_b  = (const float*)d_in[20];

    unsigned short* nv1b = (unsigned short*)d_ws;
    unsigned short* nv2b = nv1b + (size_t)BB*NN*TD;
    unsigned short* XT0  = nv2b + (size_t)BB*NN*TD;
    unsigned short* XT1  = XT0  + (size_t)BB*XTR*NN;
    unsigned short* A    = XT1  + (size_t)BB*XTR*NN;
    unsigned short* BcTg = A    + (size_t)BB*NN*KP;
    unsigned short* BcTu = BcTg + (size_t)1280*KP;
    float* biasG = (float*)(BcTu + (size_t)640*KP);
    float* biasU = biasG + (size_t)NN*OG;
    float* rbuf  = biasU + (size_t)NN*OU;
    float* out   = (float*)d_out;

    k_pre<<<dim3(2608), 256, 0, stream>>>(x, state, ne0, ne1, ne2,
        f1w1, f1b1, f1w2, f1b2, f1w3, f1b3,
        f2w1, f2b1, f2w2, f2b2, f2w3, f2b3,
        gate_w, gate_b, upd_w, upd_b,
        nv1b, nv2b, XT0, XT1, BcTg, BcTu, biasG, biasU);

    k_aapply<<<dim3(512), 256, 0, stream>>>(nv1b, nv2b, XT0, A);

    k_gemm<OG,0><<<dim3(BB*NN/128, 8), 256, 0, stream>>>(A, BcTg, ne2, biasG,
                                                         state, XT1, rbuf, nullptr);

    k_aapply<<<dim3(512), 256, 0, stream>>>(nv1b, nv2b, XT1, A);

    k_gemm<OU,1><<<dim3(BB*NN/128, 4), 256, 0, stream>>>(A, BcTu, ne2, biasU,
                                                         state, nullptr, rbuf, out);
}

// Round 10
// 235.663 us; speedup vs baseline: 1.4135x; 1.0819x over previous
//
#include <hip/hip_runtime.h>
#include <math.h>

#define BB   32      // batch
#define NN   1024    // nodes
#define DIN  2
#define DOUT 64
#define CIN  66      // DIN + DOUT
#define TD   32
#define ED   10
#define OG   128     // 2*DOUT (gate out)
#define OU   64      // upd out
#define KP   160     // padded K for the einsum GEMM (132 real)
#define XTR  80      // XT rows per batch (68 data + 12 zero pad)
#define PS   88      // s_p stride (shorts): 16B-aligned, 2-way banks only

typedef __bf16 bf16x8 __attribute__((ext_vector_type(8)));
typedef float  f32x4  __attribute__((ext_vector_type(4)));
typedef short  s16x8  __attribute__((ext_vector_type(8)));

__device__ __forceinline__ unsigned short f2b(float f) {
    __bf16 h = (__bf16)f;
    return *(unsigned short*)&h;
}

// ---------------------------------------------------------------------------
// K_PRE (R7-proven): heterogeneous preprocessing, one dispatch.
// ---------------------------------------------------------------------------
__global__ __launch_bounds__(256) void k_pre(
    const float* __restrict__ x, const float* __restrict__ state,
    const float* __restrict__ ne0, const float* __restrict__ ne1,
    const float* __restrict__ ne2,
    const float* __restrict__ w11, const float* __restrict__ b11,
    const float* __restrict__ w12, const float* __restrict__ b12,
    const float* __restrict__ w13, const float* __restrict__ b13,
    const float* __restrict__ w21, const float* __restrict__ b21,
    const float* __restrict__ w22, const float* __restrict__ b22,
    const float* __restrict__ w23, const float* __restrict__ b23,
    const float* __restrict__ gate_w, const float* __restrict__ gate_b,
    const float* __restrict__ upd_w, const float* __restrict__ upd_b,
    unsigned short* __restrict__ nv1b, unsigned short* __restrict__ nv2b,
    unsigned short* __restrict__ XT0, unsigned short* __restrict__ XT1,
    unsigned short* __restrict__ BcTg, unsigned short* __restrict__ BcTu,
    float* __restrict__ biasG, float* __restrict__ biasU)
{
    __shared__ float sw[2408];
    __shared__ unsigned short st[68*72];
    int blk = blockIdx.x;
    int t = threadIdx.x;

    if (blk < 128) {
        const int oW1 = 0, oB1 = 1056, oW2 = 1072, oB2 = 1104, oW3 = 1108, oB3 = 1172, F2 = 1204;
        for (int i = t; i < 1056; i += 256) { sw[oW1+i] = w11[i]; sw[F2+oW1+i] = w21[i]; }
        if (t < 16) { sw[oB1+t] = b11[t]; sw[F2+oB1+t] = b21[t]; }
        if (t < 32) { sw[oW2+t] = w12[t]; sw[F2+oW2+t] = w22[t]; }
        if (t < 2)  { sw[oB2+t] = b12[t]; sw[F2+oB2+t] = b22[t]; }
        if (t < 64) { sw[oW3+t] = w13[t]; sw[F2+oW3+t] = w23[t]; }
        if (t >= 64 && t < 96) { sw[oB3+t-64] = b13[t-64]; sw[F2+oB3+t-64] = b23[t-64]; }
        __syncthreads();

        int p = blk*256 + t;
        int b = p >> 10;

        float h1a[16], h1b[16];
        #pragma unroll
        for (int j = 0; j < 16; ++j) { h1a[j] = sw[oB1+j]; h1b[j] = sw[F2+oB1+j]; }
        for (int i = 0; i < CIN; ++i) {
            float v = (i < DIN) ? x[(size_t)p*DIN + i] : state[(size_t)p*DOUT + (i-DIN)];
            #pragma unroll
            for (int jq = 0; jq < 4; ++jq) {
                float4 wa = *(const float4*)&sw[oW1 + i*16 + jq*4];
                float4 wb = *(const float4*)&sw[F2 + oW1 + i*16 + jq*4];
                h1a[jq*4+0] += v*wa.x; h1a[jq*4+1] += v*wa.y;
                h1a[jq*4+2] += v*wa.z; h1a[jq*4+3] += v*wa.w;
                h1b[jq*4+0] += v*wb.x; h1b[jq*4+1] += v*wb.y;
                h1b[jq*4+2] += v*wb.z; h1b[jq*4+3] += v*wb.w;
            }
        }
        #pragma unroll
        for (int j = 0; j < 16; ++j) {
            h1a[j] = 1.f/(1.f + __expf(-h1a[j]));
            h1b[j] = 1.f/(1.f + __expf(-h1b[j]));
        }
        float h2a0 = sw[oB2+0], h2a1 = sw[oB2+1];
        float h2b0 = sw[F2+oB2+0], h2b1 = sw[F2+oB2+1];
        #pragma unroll
        for (int i = 0; i < 16; ++i) {
            h2a0 += h1a[i]*sw[oW2 + i*2 + 0];
            h2a1 += h1a[i]*sw[oW2 + i*2 + 1];
            h2b0 += h1b[i]*sw[F2+oW2 + i*2 + 0];
            h2b1 += h1b[i]*sw[F2+oW2 + i*2 + 1];
        }
        h2a0 = 1.f/(1.f + __expf(-h2a0)); h2a1 = 1.f/(1.f + __expf(-h2a1));
        h2b0 = 1.f/(1.f + __expf(-h2b0)); h2b1 = 1.f/(1.f + __expf(-h2b1));

        const float* pn0 = ne0 + b*TD;
        const float* pn1 = ne1 + b*TD;
        #pragma unroll
        for (int jq = 0; jq < 8; ++jq) {
            float4 ba  = *(const float4*)&sw[oB3 + jq*4];
            float4 wa0 = *(const float4*)&sw[oW3 + jq*4];
            float4 wa1 = *(const float4*)&sw[oW3 + 32 + jq*4];
            float4 bb2 = *(const float4*)&sw[F2+oB3 + jq*4];
            float4 wb0 = *(const float4*)&sw[F2+oW3 + jq*4];
            float4 wb1 = *(const float4*)&sw[F2+oW3 + 32 + jq*4];
            float4 n0 = *(const float4*)&pn0[jq*4];
            float4 n1 = *(const float4*)&pn1[jq*4];
            ushort4 u1, u2;
            u1.x = f2b(tanhf(n0.x*(ba.x + h2a0*wa0.x + h2a1*wa1.x)));
            u1.y = f2b(tanhf(n0.y*(ba.y + h2a0*wa0.y + h2a1*wa1.y)));
            u1.z = f2b(tanhf(n0.z*(ba.z + h2a0*wa0.z + h2a1*wa1.z)));
            u1.w = f2b(tanhf(n0.w*(ba.w + h2a0*wa0.w + h2a1*wa1.w)));
            u2.x = f2b(tanhf(n1.x*(bb2.x + h2b0*wb0.x + h2b1*wb1.x)));
            u2.y = f2b(tanhf(n1.y*(bb2.y + h2b0*wb0.y + h2b1*wb1.y)));
            u2.z = f2b(tanhf(n1.z*(bb2.z + h2b0*wb0.z + h2b1*wb1.z)));
            u2.w = f2b(tanhf(n1.w*(bb2.w + h2b0*wb0.w + h2b1*wb1.w)));
            *(ushort4*)&nv1b[(size_t)p*TD + jq*4] = u1;
            *(ushort4*)&nv2b[(size_t)p*TD + jq*4] = u2;
        }
    } else if (blk < 640) {
        int idx = blk - 128;
        int b = idx >> 4, m0 = (idx & 15)*64;
        for (int i = t; i < 1024; i += 256) {
            int m = i >> 4, cq = i & 15;
            size_t base = (size_t)b*NN + m0 + m;
            float4 v = *(const float4*)&state[base*DOUT + cq*4];
            st[(2 + cq*4 + 0)*72 + m] = f2b(v.x);
            st[(2 + cq*4 + 1)*72 + m] = f2b(v.y);
            st[(2 + cq*4 + 2)*72 + m] = f2b(v.z);
            st[(2 + cq*4 + 3)*72 + m] = f2b(v.w);
        }
        if (t < 128) {
            int m = t >> 1, c = t & 1;
            st[c*72 + m] = f2b(x[((size_t)b*NN + m0 + m)*DIN + c]);
        }
        __syncthreads();
        const unsigned int ONE2 = 0x3F803F80u;
        for (int i = t; i < XTR*8; i += 256) {
            int c = i >> 3, ch = i & 7;
            uint4 v;
            if (c < 66)      v = *(const uint4*)&st[c*72 + ch*8];
            else if (c == 66) v = make_uint4(ONE2, ONE2, ONE2, ONE2);
            else              v = make_uint4(0, 0, 0, 0);
            *(uint4*)&XT0[((size_t)b*XTR + c)*NN + m0 + ch*8] = v;
            if (c < 2 || c >= 66)
                *(uint4*)&XT1[((size_t)b*XTR + c)*NN + m0 + ch*8] = v;
        }
    } else if (blk < 1840) {
        int tid = (blk - 640)*256 + t;
        int c = tid / KP, k = tid - c*KP;
        const float* pool; int O, cc; unsigned short* dst;
        if (c < 1280) { pool = gate_w; O = OG; cc = c;        dst = BcTg; }
        else          { pool = upd_w;  O = OU; cc = c - 1280; dst = BcTu; }
        int d = cc / O, o = cc - d*O;
        float v = 0.f;
        if (k < 132) {
            int kp = (k < 66) ? 0 : 1;
            int i  = (k < 66) ? k : k - 66;
            v = pool[(size_t)((d*4 + kp)*CIN + i)*O + o]
              + pool[(size_t)((d*4 + kp + 2)*CIN + i)*O + o];
        }
        dst[(size_t)cc*KP + k] = f2b(v);
    } else {
        int i = (blk - 1840)*256 + t;
        int n = i / 192, j = i - n*192;
        float v = 0.f;
        if (j < 128) {
            #pragma unroll
            for (int d = 0; d < ED; ++d) v += ne2[(size_t)n*ED + d]*gate_b[d*OG + j];
            biasG[(size_t)n*OG + j] = v;
        } else {
            int o = j - 128;
            #pragma unroll
            for (int d = 0; d < ED; ++d) v += ne2[(size_t)n*ED + d]*upd_b[d*OU + o];
            biasU[(size_t)n*OU + o] = v;
        }
    }
}

// ---------------------------------------------------------------------------
// K_AAPPLY v6: 512 threads (8 waves), paired waves per 16-row group.
//   group g = w>>1 owns rows 16g..16g+15; sub = w&1:
//     S phase:  sub0 -> col-tiles j0t {0,1};  sub1 -> {2,3}
//     PV phase: sub0 -> out-tiles {0,1,2};    sub1 -> {3,4} (incl rowsum col 66)
// Cross-wave P -> one extra barrier/iter; waves/CU 8 -> 16 at same grid=512.
// XCD swizzle: b = id&31 -> all row-blocks of batch b on XCD b%8.
// ---------------------------------------------------------------------------
__global__ __launch_bounds__(512) void k_aapply(
    const unsigned short* __restrict__ nv1b, const unsigned short* __restrict__ nv2b,
    const unsigned short* __restrict__ XTg, unsigned short* __restrict__ A)
{
    __shared__ unsigned short s_nv1r[64*40], s_nv2r[64*40];
    __shared__ unsigned short s_nv1c[64*40], s_nv2c[64*40];
    __shared__ unsigned short s_p[64*PS];
    __shared__ unsigned short s_xt[80*72];
    __shared__ float s_rs[64];

    int t = threadIdx.x;
    int id = blockIdx.x;
    int b = id & 31, rbase = (id >> 5)*64;
    int w = t >> 6, lane = t & 63, lq = lane >> 4, ln = lane & 15;
    int g = w >> 1, sub = w & 1;

    {   // row nv staging: 512 items, one per thread
        int arr = t >> 8, j = t & 255;
        int node = j >> 2, ch = j & 3;
        const unsigned short* src = (arr ? nv2b : nv1b)
            + ((size_t)b*NN + rbase + node)*TD + ch*8;
        unsigned short* dst = (arr ? s_nv2r : s_nv1r) + node*40 + ch*8;
        *(uint4*)dst = *(const uint4*)src;
    }
    __syncthreads();

    bf16x8 a1 = *(const bf16x8*)&s_nv1r[(16*g + ln)*40 + lq*8];
    s16x8 a2s = *(const s16x8*)&s_nv2r[(16*g + ln)*40 + lq*8];
    const s16x8 sgn = {(short)0x8000,(short)0x8000,(short)0x8000,(short)0x8000,
                       (short)0x8000,(short)0x8000,(short)0x8000,(short)0x8000};
    a2s ^= sgn;
    bf16x8 a2n = (bf16x8)a2s;

    f32x4 acc[3];                            // sub0 uses 3, sub1 uses 2
    #pragma unroll
    for (int i = 0; i < 3; ++i) acc[i] = (f32x4){0.f,0.f,0.f,0.f};
    const f32x4 zero4 = {0.f,0.f,0.f,0.f};

    for (int mb = 0; mb < NN; mb += 64) {
        __syncthreads();                     // prior iter's LDS reads done
        {   // col nv staging: 512 items
            int arr = t >> 8, j = t & 255;
            int node = j >> 2, ch = j & 3;
            const unsigned short* src = (arr ? nv2b : nv1b)
                + ((size_t)b*NN + mb + node)*TD + ch*8;
            unsigned short* dst = (arr ? s_nv2c : s_nv1c) + node*40 + ch*8;
            *(uint4*)dst = *(const uint4*)src;
        }
        for (int i = t; i < 640; i += 512) { // xt staging: 640 items
            int c = i >> 3, ch = i & 7;
            *(uint4*)&s_xt[c*72 + ch*8] =
                *(const uint4*)&XTg[((size_t)b*XTR + c)*NN + mb + ch*8];
        }
        __syncthreads();

        // ---- S phase: this wave's 2 col-tiles
        #pragma unroll
        for (int jj = 0; jj < 2; ++jj) {
            int j0 = (sub*2 + jj)*16;
            bf16x8 b2 = *(const bf16x8*)&s_nv2c[(j0 + ln)*40 + lq*8];
            bf16x8 b1 = *(const bf16x8*)&s_nv1c[(j0 + ln)*40 + lq*8];
            f32x4 s = __builtin_amdgcn_mfma_f32_16x16x32_bf16(a1,  b2, zero4, 0, 0, 0);
            s       = __builtin_amdgcn_mfma_f32_16x16x32_bf16(a2n, b1, s,     0, 0, 0);
            #pragma unroll
            for (int r = 0; r < 4; ++r) {
                float p = fmaxf(s[r], 0.f);
                *(__bf16*)&s_p[(16*g + lq*4 + r)*PS + j0 + ln] = (__bf16)p;
            }
        }
        __syncthreads();                     // P visible cross-wave

        // ---- PV phase: this wave's out-tiles
        bf16x8 pa0 = *(const bf16x8*)&s_p[(16*g + ln)*PS +      lq*8];
        bf16x8 pa1 = *(const bf16x8*)&s_p[(16*g + ln)*PS + 32 + lq*8];
        if (sub == 0) {
            #pragma unroll
            for (int k = 0; k < 3; ++k) {
                int n0 = k*16;
                bf16x8 xb0 = *(const bf16x8*)&s_xt[(n0 + ln)*72 +      lq*8];
                bf16x8 xb1 = *(const bf16x8*)&s_xt[(n0 + ln)*72 + 32 + lq*8];
                acc[k] = __builtin_amdgcn_mfma_f32_16x16x32_bf16(pa0, xb0, acc[k], 0, 0, 0);
                acc[k] = __builtin_amdgcn_mfma_f32_16x16x32_bf16(pa1, xb1, acc[k], 0, 0, 0);
            }
        } else {
            #pragma unroll
            for (int k = 0; k < 2; ++k) {
                int n0 = (3 + k)*16;
                bf16x8 xb0 = *(const bf16x8*)&s_xt[(n0 + ln)*72 +      lq*8];
                bf16x8 xb1 = *(const bf16x8*)&s_xt[(n0 + ln)*72 + 32 + lq*8];
                acc[k] = __builtin_amdgcn_mfma_f32_16x16x32_bf16(pa0, xb0, acc[k], 0, 0, 0);
                acc[k] = __builtin_amdgcn_mfma_f32_16x16x32_bf16(pa1, xb1, acc[k], 0, 0, 0);
            }
        }
    }

    // rowsum = global out col 66 -> sub1 tile index 1 (n0t=4), lane col ln==2
    if (sub == 1 && ln == 2) {
        #pragma unroll
        for (int r = 0; r < 4; ++r) s_rs[16*g + lq*4 + r] = acc[1][r];
    }
    __syncthreads();
    float rinv[4];
    #pragma unroll
    for (int r = 0; r < 4; ++r) rinv[r] = 1.0f / (1.0f + s_rs[16*g + lq*4 + r]);

    int kmax = sub ? 2 : 3;
    for (int k = 0; k < kmax; ++k) {
        int c = (sub ? (3 + k) : k)*16 + ln;
        if (c < CIN) {
            #pragma unroll
            for (int r = 0; r < 4; ++r) {
                int gr = rbase + 16*g + lq*4 + r;
                size_t rowG = (size_t)b*NN + gr;
                unsigned short xu = XTg[((size_t)b*XTR + c)*NN + gr];
                float xr = (float)(*(const __bf16*)&xu);
                A[rowG*KP + c]      = xu;
                A[rowG*KP + 66 + c] = f2b((acc[k][r] + xr) * rinv[r]);
            }
        }
    }
    for (int i = t; i < 64*28; i += 512) {
        int rr = i / 28, cc = 132 + (i - 28*(i/28));
        A[((size_t)b*NN + rbase + rr)*KP + cc] = 0;
    }
}

// ---------------------------------------------------------------------------
// K_GEMM v5 (R7-proven): half-B resident (26.9 KB), two halves with restage
// barriers; ne2/bias direct from global; wave = 32 rows.
// ---------------------------------------------------------------------------
template<int O, int MODE>
__global__ __launch_bounds__(256) void k_gemm(
    const unsigned short* __restrict__ A, const unsigned short* __restrict__ BcT,
    const float* __restrict__ ne2, const float* __restrict__ biasP,
    const float* __restrict__ state, unsigned short* __restrict__ XT1,
    float* __restrict__ rbuf, float* __restrict__ out)
{
    __shared__ unsigned short s_b[80*168];

    int t = threadIdx.x;
    int w = t >> 6, lane = t & 63, lq = lane >> 4, ln = lane & 15;
    int o0 = blockIdx.y*16;
    int rowBlock = blockIdx.x*128;
    int rowW = rowBlock + w*32;

    f32x4 acc[2][2][5];
    #pragma unroll
    for (int h = 0; h < 2; ++h)
        #pragma unroll
        for (int f = 0; f < 2; ++f)
            #pragma unroll
            for (int c = 0; c < 5; ++c) acc[h][f][c] = (f32x4){0.f,0.f,0.f,0.f};

    #pragma unroll
    for (int h = 0; h < 2; ++h) {
        if (h) __syncthreads();
        for (int i = t; i < 1600; i += 256) {
            int cc = i / 20, kc = i - cc*20;
            int d = h*5 + (cc >> 4), oo = cc & 15;
            *(uint4*)&s_b[cc*168 + kc*8] =
                *(const uint4*)&BcT[(size_t)(d*O + o0 + oo)*KP + kc*8];
        }
        __syncthreads();

        #pragma unroll
        for (int kc = 0; kc < 5; ++kc) {
            bf16x8 af0 = *(const bf16x8*)&A[(size_t)(rowW      + ln)*KP + kc*32 + lq*8];
            bf16x8 af1 = *(const bf16x8*)&A[(size_t)(rowW + 16 + ln)*KP + kc*32 + lq*8];
            #pragma unroll
            for (int ct = 0; ct < 5; ++ct) {
                bf16x8 bf = *(const bf16x8*)&s_b[(ct*16 + ln)*168 + kc*32 + lq*8];
                acc[h][0][ct] = __builtin_amdgcn_mfma_f32_16x16x32_bf16(af0, bf, acc[h][0][ct], 0, 0, 0);
                acc[h][1][ct] = __builtin_amdgcn_mfma_f32_16x16x32_bf16(af1, bf, acc[h][1][ct], 0, 0, 0);
            }
        }
    }

    int o = o0 + ln;
    #pragma unroll
    for (int f = 0; f < 2; ++f) {
        #pragma unroll
        for (int r = 0; r < 4; ++r) {
            int row_l = w*32 + 16*f + lq*4 + r;
            size_t rowG = (size_t)rowBlock + row_l;
            int n = (int)(rowG & (NN - 1));
            int bb = (int)(rowG >> 10);
            const float* nep = &ne2[(size_t)n*ED];
            float val = biasP[(size_t)n*O + o];
            #pragma unroll
            for (int d = 0; d < 5; ++d) val += nep[d]     * acc[0][f][d][r];
            #pragma unroll
            for (int d = 0; d < 5; ++d) val += nep[5 + d] * acc[1][f][d][r];
            if (MODE == 0) {
                float sv = 1.f/(1.f + __expf(-val));
                if (o0 < 64) {
                    float zst = sv * state[rowG*DOUT + o];
                    XT1[((size_t)bb*XTR + 2 + o)*NN + n] = f2b(zst);
                } else {
                    rbuf[rowG*DOUT + (o - 64)] = sv;
                }
            } else {
                float hc = tanhf(val);
                float rg = rbuf[rowG*DOUT + o];
                float st = state[rowG*DOUT + o];
                out[rowG*DOUT + o] = rg*st + (1.f - rg)*hc;
            }
        }
    }
}

// ---------------------------------------------------------------------------
extern "C" void kernel_launch(void* const* d_in, const int* in_sizes, int n_in,
                              void* d_out, int out_size, void* d_ws, size_t ws_size,
                              hipStream_t stream)
{
    const float* x      = (const float*)d_in[0];
    const float* state  = (const float*)d_in[1];
    const float* ne0    = (const float*)d_in[2];
    const float* ne1    = (const float*)d_in[3];
    const float* ne2    = (const float*)d_in[4];
    const float* f1w1   = (const float*)d_in[5];
    const float* f1b1   = (const float*)d_in[6];
    const float* f1w2   = (const float*)d_in[7];
    const float* f1b2   = (const float*)d_in[8];
    const float* f1w3   = (const float*)d_in[9];
    const float* f1b3   = (const float*)d_in[10];
    const float* f2w1   = (const float*)d_in[11];
    const float* f2b1   = (const float*)d_in[12];
    const float* f2w2   = (const float*)d_in[13];
    const float* f2b2   = (const float*)d_in[14];
    const float* f2w3   = (const float*)d_in[15];
    const float* f2b3   = (const float*)d_in[16];
    const float* gate_w = (const float*)d_in[17];
    const float* gate_b = (const float*)d_in[18];
    const float* upd_w  = (const float*)d_in[19];
    const float* upd_b  = (const float*)d_in[20];

    unsigned short* nv1b = (unsigned short*)d_ws;
    unsigned short* nv2b = nv1b + (size_t)BB*NN*TD;
    unsigned short* XT0  = nv2b + (size_t)BB*NN*TD;
    unsigned short* XT1  = XT0  + (size_t)BB*XTR*NN;
    unsigned short* A    = XT1  + (size_t)BB*XTR*NN;
    unsigned short* BcTg = A    + (size_t)BB*NN*KP;
    unsigned short* BcTu = BcTg + (size_t)1280*KP;
    float* biasG = (float*)(BcTu + (size_t)640*KP);
    float* biasU = biasG + (size_t)NN*OG;
    float* rbuf  = biasU + (size_t)NN*OU;
    float* out   = (float*)d_out;

    k_pre<<<dim3(2608), 256, 0, stream>>>(x, state, ne0, ne1, ne2,
        f1w1, f1b1, f1w2, f1b2, f1w3, f1b3,
        f2w1, f2b1, f2w2, f2b2, f2w3, f2b3,
        gate_w, gate_b, upd_w, upd_b,
        nv1b, nv2b, XT0, XT1, BcTg, BcTu, biasG, biasU);

    k_aapply<<<dim3(512), 512, 0, stream>>>(nv1b, nv2b, XT0, A);

    k_gemm<OG,0><<<dim3(BB*NN/128, 8), 256, 0, stream>>>(A, BcTg, ne2, biasG,
                                                         state, XT1, rbuf, nullptr);

    k_aapply<<<dim3(512), 512, 0, stream>>>(nv1b, nv2b, XT1, A);

    k_gemm<OU,1><<<dim3(BB*NN/128, 4), 256, 0, stream>>>(A, BcTu, ne2, biasU,
                                                         state, nullptr, rbuf, out);
}